// Round 3
// baseline (390.707 us; speedup 1.0000x reference)
//
#include <hip/hip_runtime.h>
#include <cmath>

#define BB   512
#define NSV  128
#define NTRK 512
#define KK   8
#define HH   16
#define TPB  1024          // threads 0-511: half 0 (+track MLP); 512-1023: half 1 (+SV MLP)
#define RSTR 20            // LDS row stride: [16 feats][0.5*||sv||^2][pad] — 80B, 16B-aligned
#define PSTR 20            // padded proj stride in LDS
#define TSTR 18            // tfS stride (8B-aligned for vf2 reads)

typedef float vf2 __attribute__((ext_vector_type(2)));
typedef float vf4 __attribute__((ext_vector_type(4)));

// exp2-based expm1: ~1e-7 absolute error, replaces the ~30-instr libm path.
__device__ __forceinline__ float elu_f(float x) {
    float e = __builtin_amdgcn_exp2f(x * 1.44269504088896341f) - 1.0f;
    return x > 0.0f ? x : e;
}
__device__ __forceinline__ unsigned umin_u(unsigned a, unsigned b) { return a < b ? a : b; }
__device__ __forceinline__ unsigned med3u(unsigned a, unsigned b, unsigned c) {
    unsigned d;
    asm("v_med3_u32 %0, %1, %2, %3" : "=v"(d) : "v"(a), "v"(b), "v"(c));
    return d;
}

// One block = one batch. 1024 threads, 2-way SV-scan split per track:
// thread tid handles track (tid&511) scanning SV half (tid>>9) * 64 rows.
// Rows live in LDS (broadcast ds_read_b128, in-order lgkmcnt -> real depth-3
// pipeline; the SMEM path's out-of-order s_loads forced lgkmcnt(0) drains).
// [R2 errata: vf2 buf[8] arrays written via float4 puns -> SROA failed, bufs
//  spilled to scratch, 1 GB of HBM scratch traffic, 295us. R3 uses NAMED vf4
//  registers per pipeline stage — no private arrays on the scan path.]
__global__ __launch_bounds__(TPB, 8) void fused_all(
    const float* __restrict__ x_sv, const float* __restrict__ x_trk,
    const float* __restrict__ W1s, const float* __restrict__ b1s,
    const float* __restrict__ W2s, const float* __restrict__ b2s,
    const float* __restrict__ W1t, const float* __restrict__ b1t,
    const float* __restrict__ W2t, const float* __restrict__ b2t,
    const float* __restrict__ We,  const float* __restrict__ be,
    const float* __restrict__ Wo,  const float* __restrict__ bo,
    float* __restrict__ out)
{
    __shared__ __align__(16) float rowsS[NSV][RSTR];   // 10.2 KB: sv feats + 0.5||sv||^2
    __shared__ float    proj[NSV][PSTR];               // 10.2 KB
    __shared__ float    tfS[NTRK][TSTR];               // 36.9 KB: tf[16], htsq (dead after scan starts)
    __shared__ unsigned kbuf[NTRK][KK];                // 16.4 KB: half-1 sorted lists
    __shared__ float    ucS[HH + 1];                   // u[16], c0
    __shared__ float    sred[TPB / 64];

    const int b   = blockIdx.x, tid = threadIdx.x;
    const int tl  = tid & (NTRK - 1);                             // track
    const int sh  = __builtin_amdgcn_readfirstlane(tid >> 9);     // 0/1, wave-uniform

    // ---- phase A/B in parallel across thread ranges ----
    if (tid < NTRK) {
        // track MLP, once per track -> LDS
        const float* xp = x_trk + (size_t)(b * NTRK + tid) * 8;
        float x[8];
        *(float4*)&x[0] = *(const float4*)&xp[0];
        *(float4*)&x[4] = *(const float4*)&xp[4];
        float hb[HH];
        #pragma unroll
        for (int h = 0; h < HH; ++h) {
            float a = b1t[h];
            #pragma unroll
            for (int i = 0; i < 8; ++i) a += x[i] * W1t[i * HH + h];
            hb[h] = elu_f(a);
        }
        float sq = 0.0f;
        #pragma unroll
        for (int h2 = 0; h2 < HH; ++h2) {
            float a = b2t[h2];
            #pragma unroll
            for (int h = 0; h < HH; ++h) a += hb[h] * W2t[h * HH + h2];
            tfS[tid][h2] = a;
            sq += a * a;
        }
        tfS[tid][HH] = 0.5f * sq;
    } else if (tid < NTRK + NSV) {
        // SV MLP -> LDS rows + LDS proj
        const int s = tid - NTRK;
        const float* xp = x_sv + (size_t)(b * NSV + s) * 2;
        float x0 = xp[0], x1 = xp[1];
        float hb[HH];
        #pragma unroll
        for (int h = 0; h < HH; ++h)
            hb[h] = elu_f(x0 * W1s[h] + x1 * W1s[HH + h] + b1s[h]);
        float o[HH], sq = 0.0f;
        #pragma unroll
        for (int h2 = 0; h2 < HH; ++h2) {
            float a = b2s[h2];
            #pragma unroll
            for (int h = 0; h < HH; ++h) a += hb[h] * W2s[h * HH + h2];
            o[h2] = a;
            sq += a * a;
        }
        #pragma unroll
        for (int h4 = 0; h4 < 4; ++h4)
            *(float4*)&rowsS[s][h4 * 4] = make_float4(o[h4*4], o[h4*4+1], o[h4*4+2], o[h4*4+3]);
        rowsS[s][HH] = 0.5f * sq;
        #pragma unroll
        for (int h = 0; h < HH; ++h) {
            float a = 0.0f;
            #pragma unroll
            for (int j = 0; j < HH; ++j) a += o[j] * We[(HH + j) * HH + h];
            proj[s][h] = a;
        }
    } else if (tid < NTRK + NSV + HH) {
        int j = tid - NTRK - NSV;
        float a = 0.0f;
        #pragma unroll
        for (int h = 0; h < HH; ++h)
            a += (We[j * HH + h] - We[(HH + j) * HH + h]) * Wo[h];
        ucS[j] = a;
    } else if (tid == NTRK + NSV + HH) {
        float a = bo[0];
        #pragma unroll
        for (int h = 0; h < HH; ++h) a += be[h] * Wo[h];
        ucS[HH] = a;
    }

    __syncthreads();   // rowsS/proj/uc/tf staged

    // ---- read my track's tf/htsq from LDS (one-time), negate into 4 vf4 regs ----
    vf2 t0 = *(const vf2*)&tfS[tl][0],  t1 = *(const vf2*)&tfS[tl][2];
    vf2 t2 = *(const vf2*)&tfS[tl][4],  t3 = *(const vf2*)&tfS[tl][6];
    vf2 t4 = *(const vf2*)&tfS[tl][8],  t5 = *(const vf2*)&tfS[tl][10];
    vf2 t6 = *(const vf2*)&tfS[tl][12], t7 = *(const vf2*)&tfS[tl][14];
    float htsq = tfS[tl][HH];
    vf4 nA, nB, nC, nD;
    nA.x = -t0.x; nA.y = -t0.y; nA.z = -t1.x; nA.w = -t1.y;
    nB.x = -t2.x; nB.y = -t2.y; nB.z = -t3.x; nB.w = -t3.y;
    nC.x = -t4.x; nC.y = -t4.y; nC.z = -t5.x; nC.w = -t5.y;
    nD.x = -t6.x; nD.y = -t6.y; nD.z = -t7.x; nD.w = -t7.y;

    __syncthreads();   // tfS now provably dead -> half 0 may reuse it as kbuf0

    unsigned k[KK];
    #pragma unroll
    for (int q = 0; q < KK; ++q) k[q] = 0xFFFFFFFFu;

    // ---- kNN scan of this half's 64 LDS rows: broadcast ds_read, depth-3 ----
    const int sbase = sh * 64;

    // NAMED registers per pipeline stage (no private arrays -> no scratch).
    vf4 p0A, p0B, p0C, p0D, p1A, p1B, p1C, p1D, p2A, p2B, p2C, p2D;
    float h0, h1, h2;

    #define LOADROW(A, B_, C, D, hv, idx)                              \
        do {                                                           \
            const float* _r = &rowsS[sbase + (idx)][0];                \
            A  = *(const vf4*)(_r + 0);                                \
            B_ = *(const vf4*)(_r + 4);                                \
            C  = *(const vf4*)(_r + 8);                                \
            D  = *(const vf4*)(_r + 12);                               \
            hv = _r[HH];                                               \
        } while (0)

    #define BODY(A, B_, C, D, hv, idx)                                 \
        do {                                                           \
            vf4 m0 = nA * A;                                           \
            vf4 m1 = nB * B_;                                          \
            m0 = __builtin_elementwise_fma(nC, C, m0);                 \
            m1 = __builtin_elementwise_fma(nD, D, m1);                 \
            m0 = m0 + m1;                                              \
            float e = fmaxf((htsq + hv) + ((m0.x + m0.y) + (m0.z + m0.w)), 0.0f); \
            unsigned v = (__float_as_uint(e) & 0xFFFFFF80u)            \
                         | (unsigned)(sbase + (idx));                  \
            unsigned nk0 = umin_u(v, k[0]);                            \
            unsigned nk1 = med3u(v, k[0], k[1]);                       \
            unsigned nk2 = med3u(v, k[1], k[2]);                       \
            unsigned nk3 = med3u(v, k[2], k[3]);                       \
            unsigned nk4 = med3u(v, k[3], k[4]);                       \
            unsigned nk5 = med3u(v, k[4], k[5]);                       \
            unsigned nk6 = med3u(v, k[5], k[6]);                       \
            unsigned nk7 = med3u(v, k[6], k[7]);                       \
            k[0] = nk0; k[1] = nk1; k[2] = nk2; k[3] = nk3;            \
            k[4] = nk4; k[5] = nk5; k[6] = nk6; k[7] = nk7;            \
        } while (0)

    LOADROW(p0A, p0B, p0C, p0D, h0, 0);
    LOADROW(p1A, p1B, p1C, p1D, h1, 1);
    LOADROW(p2A, p2B, p2C, p2D, h2, 2);
    for (int s = 0; s < 60; s += 3) {
        BODY(p0A, p0B, p0C, p0D, h0, s);     LOADROW(p0A, p0B, p0C, p0D, h0, s + 3);
        BODY(p1A, p1B, p1C, p1D, h1, s + 1); LOADROW(p1A, p1B, p1C, p1D, h1, s + 4);
        BODY(p2A, p2B, p2C, p2D, h2, s + 2); LOADROW(p2A, p2B, p2C, p2D, h2, s + 5);
    }
    BODY(p0A, p0B, p0C, p0D, h0, 60); LOADROW(p0A, p0B, p0C, p0D, h0, 63);
    BODY(p1A, p1B, p1C, p1D, h1, 61);
    BODY(p2A, p2B, p2C, p2D, h2, 62);
    BODY(p0A, p0B, p0C, p0D, h0, 63);

    #undef LOADROW
    #undef BODY

    // ---- both halves publish sorted lists; half 0 reuses dead tfS space ----
    unsigned (*kbuf0)[KK] = reinterpret_cast<unsigned(*)[KK]>(&tfS[0][0]); // 16 KB of tfS
    float*   sred2        = &tfS[0][0] + 4096;                             // tfS floats [4096,4608)
    {
        unsigned (*dst)[KK] = sh ? kbuf : kbuf0;     // sh is wave-uniform
        #pragma unroll
        for (int q = 0; q < KK; ++q) dst[tl][q] = k[q];
    }
    __syncthreads();

    // ---- both halves: exact merge (same SET on both sides) + h-split epilogue ----
    unsigned (*kb_other)[KK] = sh ? kbuf0 : kbuf;
    unsigned m[KK];    // exact 8-smallest of union (bitonic set, unsorted)
    #pragma unroll
    for (int i = 0; i < KK; ++i) m[i] = umin_u(k[i], kb_other[tl][KK - 1 - i]);

    // half sh handles output dims [8*sh, 8*sh+8); -n = tf
    float acc = (sh == 0) ? ucS[HH] : 0.0f;
    {
        vf4 u0 = sh ? nC : nA;
        vf4 u1 = sh ? nD : nB;
        const float* uc = &ucS[8 * sh];
        acc = fmaf(-u0.x, uc[0], acc);
        acc = fmaf(-u0.y, uc[1], acc);
        acc = fmaf(-u0.z, uc[2], acc);
        acc = fmaf(-u0.w, uc[3], acc);
        acc = fmaf(-u1.x, uc[4], acc);
        acc = fmaf(-u1.y, uc[5], acc);
        acc = fmaf(-u1.z, uc[6], acc);
        acc = fmaf(-u1.w, uc[7], acc);
    }
    float mx[8];
    #pragma unroll
    for (int h = 0; h < 8; ++h) mx[h] = -INFINITY;
    #pragma unroll
    for (int q = 0; q < KK; ++q) {
        const float* pr = &proj[m[q] & 127u][8 * sh];
        #pragma unroll
        for (int h4 = 0; h4 < 2; ++h4) {
            float4 p = *(const float4*)&pr[h4 * 4];
            mx[h4 * 4 + 0] = fmaxf(mx[h4 * 4 + 0], p.x);
            mx[h4 * 4 + 1] = fmaxf(mx[h4 * 4 + 1], p.y);
            mx[h4 * 4 + 2] = fmaxf(mx[h4 * 4 + 2], p.z);
            mx[h4 * 4 + 3] = fmaxf(mx[h4 * 4 + 3], p.w);
        }
    }
    #pragma unroll
    for (int h = 0; h < 8; ++h) acc = fmaf(mx[h], Wo[8 * sh + h], acc);

    if (sh == 1) sred2[tl] = acc;     // partial (dims 8..15) -> half 0
    __syncthreads();

    float local = 0.0f;
    if (sh == 0) {
        float a = acc + sred2[tl];
        // sigmoid via v_exp_f32 + v_rcp_f32
        float t = __builtin_amdgcn_exp2f(a * -1.44269504088896341f);
        local = __builtin_amdgcn_rcpf(1.0f + t);
    }

    // ---- block mean-pool (half 1 contributes zeros) ----
    #pragma unroll
    for (int off = 32; off > 0; off >>= 1)
        local += __shfl_down(local, off, 64);
    if ((tid & 63) == 0) sred[tid >> 6] = local;
    __syncthreads();
    if (tid == 0) {
        float tot = 0.0f;
        #pragma unroll
        for (int w = 0; w < TPB / 64; ++w) tot += sred[w];
        out[b]      = tot * (1.0f / NTRK);
        out[BB + b] = (float)b;
    }
}

extern "C" void kernel_launch(void* const* d_in, const int* in_sizes, int n_in,
                              void* d_out, int out_size, void* d_ws, size_t ws_size,
                              hipStream_t stream) {
    const float* x_sv  = (const float*)d_in[0];
    const float* x_trk = (const float*)d_in[1];
    const float* W1s = (const float*)d_in[4];
    const float* b1s = (const float*)d_in[5];
    const float* W2s = (const float*)d_in[6];
    const float* b2s = (const float*)d_in[7];
    const float* W1t = (const float*)d_in[8];
    const float* b1t = (const float*)d_in[9];
    const float* W2t = (const float*)d_in[10];
    const float* b2t = (const float*)d_in[11];
    const float* We  = (const float*)d_in[12];
    const float* be  = (const float*)d_in[13];
    const float* Wo  = (const float*)d_in[14];
    const float* bo  = (const float*)d_in[15];
    float* out = (float*)d_out;

    fused_all<<<BB, TPB, 0, stream>>>(x_sv, x_trk,
                                      W1s, b1s, W2s, b2s,
                                      W1t, b1t, W2t, b2t,
                                      We, be, Wo, bo,
                                      out);
}

// Round 4
// 143.367 us; speedup vs baseline: 2.7252x; 2.7252x over previous
//
#include <hip/hip_runtime.h>
#include <cmath>

#define BB   512
#define NSV  128
#define NTRK 512
#define KK   8
#define HH   16
#define TPB  512           // one thread per track; threads 0-127 also run the SV MLP
#define RSTR 20            // LDS row stride: [16 feats][0.5*||sv||^2][pad] — 80B, 16B-aligned
#define PSTR 20            // padded proj stride in LDS

typedef float vf2 __attribute__((ext_vector_type(2)));
typedef float vf4 __attribute__((ext_vector_type(4)));

// exp2-based expm1: ~1e-7 absolute error, replaces the ~30-instr libm path.
__device__ __forceinline__ float elu_f(float x) {
    float e = __builtin_amdgcn_exp2f(x * 1.44269504088896341f) - 1.0f;
    return x > 0.0f ? x : e;
}
__device__ __forceinline__ unsigned umin_u(unsigned a, unsigned b) { return a < b ? a : b; }
__device__ __forceinline__ unsigned med3u(unsigned a, unsigned b, unsigned c) {
    unsigned d;
    asm("v_med3_u32 %0, %1, %2, %3" : "=v"(d) : "v"(a), "v"(b), "v"(c));
    return d;
}

// One block = one batch, 512 threads = one thread per track.
// Track MLP entirely in registers (no tfS LDS). SV rows + proj in LDS.
// kNN scan: 128 broadcast ds_read rows, depth-3 pipeline of NAMED vf4 regs.
// [R3 errata: __launch_bounds__(1024,8) capped VGPRs at ~64 -> the ds_read
//  pipeline spilled (750MB scratch). (512,4) gives a 128-VGPR budget; the
//  scan needs ~85. LDS now 20.6KB; occupancy 2 blocks/CU (VGPR-bound).]
// [R2 errata: private vf2 arrays + float4 puns -> SROA failure, 1GB scratch.]
__global__ __launch_bounds__(TPB, 4) void fused_all(
    const float* __restrict__ x_sv, const float* __restrict__ x_trk,
    const float* __restrict__ W1s, const float* __restrict__ b1s,
    const float* __restrict__ W2s, const float* __restrict__ b2s,
    const float* __restrict__ W1t, const float* __restrict__ b1t,
    const float* __restrict__ W2t, const float* __restrict__ b2t,
    const float* __restrict__ We,  const float* __restrict__ be,
    const float* __restrict__ Wo,  const float* __restrict__ bo,
    float* __restrict__ out)
{
    __shared__ __align__(16) float rowsS[NSV][RSTR];   // 10.2 KB: sv feats + 0.5||sv||^2
    __shared__ __align__(16) float proj[NSV][PSTR];    // 10.2 KB
    __shared__ float ucS[HH + 1];                      // u[16], c0
    __shared__ float sred[TPB / 64];

    const int b   = blockIdx.x, tid = threadIdx.x;

    // ---- track MLP: every thread, own track, stays in registers ----
    float tf[HH];
    float htsq;
    {
        const float* xp = x_trk + (size_t)(b * NTRK + tid) * 8;
        float x[8];
        *(float4*)&x[0] = *(const float4*)&xp[0];
        *(float4*)&x[4] = *(const float4*)&xp[4];
        float hb[HH];
        #pragma unroll
        for (int h = 0; h < HH; ++h) {
            float a = b1t[h];
            #pragma unroll
            for (int i = 0; i < 8; ++i) a += x[i] * W1t[i * HH + h];
            hb[h] = elu_f(a);
        }
        float sq = 0.0f;
        #pragma unroll
        for (int h2 = 0; h2 < HH; ++h2) {
            float a = b2t[h2];
            #pragma unroll
            for (int h = 0; h < HH; ++h) a += hb[h] * W2t[h * HH + h2];
            tf[h2] = a;
            sq += a * a;
        }
        htsq = 0.5f * sq;
    }

    // ---- SV MLP on threads 0-127 -> LDS rows + proj; uc on 128-144 ----
    if (tid < NSV) {
        const float* xp = x_sv + (size_t)(b * NSV + tid) * 2;
        float x0 = xp[0], x1 = xp[1];
        float hb[HH];
        #pragma unroll
        for (int h = 0; h < HH; ++h)
            hb[h] = elu_f(x0 * W1s[h] + x1 * W1s[HH + h] + b1s[h]);
        float o[HH], sq = 0.0f;
        #pragma unroll
        for (int h2 = 0; h2 < HH; ++h2) {
            float a = b2s[h2];
            #pragma unroll
            for (int h = 0; h < HH; ++h) a += hb[h] * W2s[h * HH + h2];
            o[h2] = a;
            sq += a * a;
        }
        #pragma unroll
        for (int h4 = 0; h4 < 4; ++h4)
            *(float4*)&rowsS[tid][h4 * 4] = make_float4(o[h4*4], o[h4*4+1], o[h4*4+2], o[h4*4+3]);
        rowsS[tid][HH] = 0.5f * sq;
        #pragma unroll
        for (int h = 0; h < HH; ++h) {
            float a = 0.0f;
            #pragma unroll
            for (int j = 0; j < HH; ++j) a += o[j] * We[(HH + j) * HH + h];
            proj[tid][h] = a;
        }
    } else if (tid < NSV + HH) {
        int j = tid - NSV;
        float a = 0.0f;
        #pragma unroll
        for (int h = 0; h < HH; ++h)
            a += (We[j * HH + h] - We[(HH + j) * HH + h]) * Wo[h];
        ucS[j] = a;
    } else if (tid == NSV + HH) {
        float a = bo[0];
        #pragma unroll
        for (int h = 0; h < HH; ++h) a += be[h] * Wo[h];
        ucS[HH] = a;
    }

    // pack -tf into 4 vf4 regs for the scan
    vf4 nA, nB, nC, nD;
    nA.x = -tf[0];  nA.y = -tf[1];  nA.z = -tf[2];  nA.w = -tf[3];
    nB.x = -tf[4];  nB.y = -tf[5];  nB.z = -tf[6];  nB.w = -tf[7];
    nC.x = -tf[8];  nC.y = -tf[9];  nC.z = -tf[10]; nC.w = -tf[11];
    nD.x = -tf[12]; nD.y = -tf[13]; nD.z = -tf[14]; nD.w = -tf[15];

    __syncthreads();   // rowsS/proj/uc staged

    unsigned k[KK];
    #pragma unroll
    for (int q = 0; q < KK; ++q) k[q] = 0xFFFFFFFFu;

    // ---- kNN scan of all 128 LDS rows: broadcast ds_read, depth-3 ----
    // NAMED registers per pipeline stage (no private arrays -> no scratch).
    vf4 p0A, p0B, p0C, p0D, p1A, p1B, p1C, p1D, p2A, p2B, p2C, p2D;
    float h0, h1, h2;

    #define LOADROW(A, B_, C, D, hv, idx)                              \
        do {                                                           \
            const float* _r = &rowsS[(idx)][0];                        \
            A  = *(const vf4*)(_r + 0);                                \
            B_ = *(const vf4*)(_r + 4);                                \
            C  = *(const vf4*)(_r + 8);                                \
            D  = *(const vf4*)(_r + 12);                               \
            hv = _r[HH];                                               \
        } while (0)

    #define BODY(A, B_, C, D, hv, idx)                                 \
        do {                                                           \
            vf4 m0 = nA * A;                                           \
            vf4 m1 = nB * B_;                                          \
            m0 = __builtin_elementwise_fma(nC, C, m0);                 \
            m1 = __builtin_elementwise_fma(nD, D, m1);                 \
            m0 = m0 + m1;                                              \
            float e = fmaxf((htsq + hv) + ((m0.x + m0.y) + (m0.z + m0.w)), 0.0f); \
            unsigned v = (__float_as_uint(e) & 0xFFFFFF80u)            \
                         | (unsigned)(idx);                            \
            unsigned nk0 = umin_u(v, k[0]);                            \
            unsigned nk1 = med3u(v, k[0], k[1]);                       \
            unsigned nk2 = med3u(v, k[1], k[2]);                       \
            unsigned nk3 = med3u(v, k[2], k[3]);                       \
            unsigned nk4 = med3u(v, k[3], k[4]);                       \
            unsigned nk5 = med3u(v, k[4], k[5]);                       \
            unsigned nk6 = med3u(v, k[5], k[6]);                       \
            unsigned nk7 = med3u(v, k[6], k[7]);                       \
            k[0] = nk0; k[1] = nk1; k[2] = nk2; k[3] = nk3;            \
            k[4] = nk4; k[5] = nk5; k[6] = nk6; k[7] = nk7;            \
        } while (0)

    LOADROW(p0A, p0B, p0C, p0D, h0, 0);
    LOADROW(p1A, p1B, p1C, p1D, h1, 1);
    LOADROW(p2A, p2B, p2C, p2D, h2, 2);
    for (int s = 0; s < 121; s += 3) {
        BODY(p0A, p0B, p0C, p0D, h0, s);     LOADROW(p0A, p0B, p0C, p0D, h0, s + 3);
        BODY(p1A, p1B, p1C, p1D, h1, s + 1); LOADROW(p1A, p1B, p1C, p1D, h1, s + 4);
        BODY(p2A, p2B, p2C, p2D, h2, s + 2); LOADROW(p2A, p2B, p2C, p2D, h2, s + 5);
    }
    // loop covered bodies 0..122, loads 3..125; pending p0=123 p1=124 p2=125
    BODY(p0A, p0B, p0C, p0D, h0, 123); LOADROW(p0A, p0B, p0C, p0D, h0, 126);
    BODY(p1A, p1B, p1C, p1D, h1, 124); LOADROW(p1A, p1B, p1C, p1D, h1, 127);
    BODY(p2A, p2B, p2C, p2D, h2, 125);
    BODY(p0A, p0B, p0C, p0D, h0, 126);
    BODY(p1A, p1B, p1C, p1D, h1, 127);

    #undef LOADROW
    #undef BODY

    // ---- epilogue: k[] IS the exact top-8 (full scan, no merge needed) ----
    float acc = ucS[HH];
    {
        const float* uc = &ucS[0];
        acc = fmaf(tf[0],  uc[0],  acc); acc = fmaf(tf[1],  uc[1],  acc);
        acc = fmaf(tf[2],  uc[2],  acc); acc = fmaf(tf[3],  uc[3],  acc);
        acc = fmaf(tf[4],  uc[4],  acc); acc = fmaf(tf[5],  uc[5],  acc);
        acc = fmaf(tf[6],  uc[6],  acc); acc = fmaf(tf[7],  uc[7],  acc);
        acc = fmaf(tf[8],  uc[8],  acc); acc = fmaf(tf[9],  uc[9],  acc);
        acc = fmaf(tf[10], uc[10], acc); acc = fmaf(tf[11], uc[11], acc);
        acc = fmaf(tf[12], uc[12], acc); acc = fmaf(tf[13], uc[13], acc);
        acc = fmaf(tf[14], uc[14], acc); acc = fmaf(tf[15], uc[15], acc);
    }
    float mx[HH];
    #pragma unroll
    for (int h = 0; h < HH; ++h) mx[h] = -INFINITY;
    #pragma unroll
    for (int q = 0; q < KK; ++q) {
        const float* pr = &proj[k[q] & 127u][0];
        #pragma unroll
        for (int h4 = 0; h4 < 4; ++h4) {
            float4 p = *(const float4*)&pr[h4 * 4];
            mx[h4 * 4 + 0] = fmaxf(mx[h4 * 4 + 0], p.x);
            mx[h4 * 4 + 1] = fmaxf(mx[h4 * 4 + 1], p.y);
            mx[h4 * 4 + 2] = fmaxf(mx[h4 * 4 + 2], p.z);
            mx[h4 * 4 + 3] = fmaxf(mx[h4 * 4 + 3], p.w);
        }
    }
    #pragma unroll
    for (int h = 0; h < HH; ++h) acc = fmaf(mx[h], Wo[h], acc);

    // sigmoid via v_exp_f32 + v_rcp_f32
    float t = __builtin_amdgcn_exp2f(acc * -1.44269504088896341f);
    float local = __builtin_amdgcn_rcpf(1.0f + t);

    // ---- block mean-pool over 512 tracks ----
    #pragma unroll
    for (int off = 32; off > 0; off >>= 1)
        local += __shfl_down(local, off, 64);
    if ((tid & 63) == 0) sred[tid >> 6] = local;
    __syncthreads();
    if (tid == 0) {
        float tot = 0.0f;
        #pragma unroll
        for (int w = 0; w < TPB / 64; ++w) tot += sred[w];
        out[b]      = tot * (1.0f / NTRK);
        out[BB + b] = (float)b;
    }
}

extern "C" void kernel_launch(void* const* d_in, const int* in_sizes, int n_in,
                              void* d_out, int out_size, void* d_ws, size_t ws_size,
                              hipStream_t stream) {
    const float* x_sv  = (const float*)d_in[0];
    const float* x_trk = (const float*)d_in[1];
    const float* W1s = (const float*)d_in[4];
    const float* b1s = (const float*)d_in[5];
    const float* W2s = (const float*)d_in[6];
    const float* b2s = (const float*)d_in[7];
    const float* W1t = (const float*)d_in[8];
    const float* b1t = (const float*)d_in[9];
    const float* W2t = (const float*)d_in[10];
    const float* b2t = (const float*)d_in[11];
    const float* We  = (const float*)d_in[12];
    const float* be  = (const float*)d_in[13];
    const float* Wo  = (const float*)d_in[14];
    const float* bo  = (const float*)d_in[15];
    float* out = (float*)d_out;

    fused_all<<<BB, TPB, 0, stream>>>(x_sv, x_trk,
                                      W1s, b1s, W2s, b2s,
                                      W1t, b1t, W2t, b2t,
                                      We, be, Wo, bo,
                                      out);
}

// Round 5
// 126.404 us; speedup vs baseline: 3.0909x; 1.1342x over previous
//
#include <hip/hip_runtime.h>
#include <cmath>

#define BB   512
#define NSV  128
#define NTRK 512
#define KK   8
#define HH   16
#define TPB  512           // 8 waves; one thread per track for MLP+epilogue
#define TST  40            // T stride in shorts (80B): [thi 16][tlo 16][htsq f32][pad]
#define SST  24            // Shi/Slo stride in shorts (48B)
#define PSTR 20            // proj stride (f32)

typedef float f32x4  __attribute__((ext_vector_type(4)));
typedef short bf16x8 __attribute__((ext_vector_type(8)));

__device__ __forceinline__ float elu_f(float x) {
    float e = __builtin_amdgcn_exp2f(x * 1.44269504088896341f) - 1.0f;
    return x > 0.0f ? x : e;
}
__device__ __forceinline__ unsigned umin_u(unsigned a, unsigned b) { return a < b ? a : b; }
__device__ __forceinline__ unsigned umax_u(unsigned a, unsigned b) { return a > b ? a : b; }
__device__ __forceinline__ unsigned med3u(unsigned a, unsigned b, unsigned c) {
    unsigned d;
    asm("v_med3_u32 %0, %1, %2, %3" : "=v"(d) : "v"(a), "v"(b), "v"(c));
    return d;
}

// One block = one batch.
// Phase A: per-thread track MLP -> split-bf16 [thi|tlo] rows + htsq into LDS;
//          threads 0-127 also SV MLP -> Shi/Slo (split-bf16) + hsq + proj.
// Phase B (MFMA): D = S·T^T per 16x16 tile via 2x mfma_f32_16x16x32_bf16
//          (A = [s_hi|s_hi] then [s_lo|s_lo] dup-K; B = [t_hi|t_lo]):
//          dot = (s_hi+s_lo)·t, err ~2^-16. C layout (m89): lane = 1 track
//          (col=lane&15) x 4 svs/reg -> 32 svs/lane over 8 sv-tiles.
//          Per-lane med3-chain top-8 over 32, then 2-stage shfl_xor merge
//          (min(a[i],b[7-i]) + bitonic-8 resort) across the 4 lanes of a track.
// Phase C: per-thread epilogue (exact f32), as R4.
// [R4 errata: LDS-broadcast scan = 61.5us: ds_read_b128 costs ~12cy/CU even
//  broadcast (64x16B writeback) -> vector-path row delivery is the wall.
//  SMEM path (44.5us) stalls on ooo lgkmcnt drains. MFMA moves the all-pairs
//  broadcast into the matrix pipe.]
__global__ __launch_bounds__(TPB, 4) void fused_all(
    const float* __restrict__ x_sv, const float* __restrict__ x_trk,
    const float* __restrict__ W1s, const float* __restrict__ b1s,
    const float* __restrict__ W2s, const float* __restrict__ b2s,
    const float* __restrict__ W1t, const float* __restrict__ b1t,
    const float* __restrict__ W2t, const float* __restrict__ b2t,
    const float* __restrict__ We,  const float* __restrict__ be,
    const float* __restrict__ Wo,  const float* __restrict__ bo,
    float* __restrict__ out)
{
    __shared__ __align__(16) short    Tsh[NTRK * TST];    // 40 KB
    __shared__ __align__(16) short    ShiS[NSV * SST];    // 6 KB
    __shared__ __align__(16) short    SloS[NSV * SST];    // 6 KB
    __shared__ __align__(16) float    hsqS[NSV];          // 0.5 KB
    __shared__ __align__(16) float    proj[NSV][PSTR];    // 10.2 KB
    __shared__ __align__(16) unsigned knnS[NTRK * KK];    // 16 KB
    __shared__ float ucS[HH + 1];
    __shared__ float sred[TPB / 64];

    const int b   = blockIdx.x, tid = threadIdx.x;

    // ================= phase A =================
    {
        // track MLP for track tid
        const float* xp = x_trk + (size_t)(b * NTRK + tid) * 8;
        float x[8];
        *(float4*)&x[0] = *(const float4*)&xp[0];
        *(float4*)&x[4] = *(const float4*)&xp[4];
        float hb[HH];
        #pragma unroll
        for (int h = 0; h < HH; ++h) {
            float a = b1t[h];
            #pragma unroll
            for (int i = 0; i < 8; ++i) a += x[i] * W1t[i * HH + h];
            hb[h] = elu_f(a);
        }
        float tf[HH], sq = 0.0f;
        #pragma unroll
        for (int h2 = 0; h2 < HH; ++h2) {
            float a = b2t[h2];
            #pragma unroll
            for (int h = 0; h < HH; ++h) a += hb[h] * W2t[h * HH + h2];
            tf[h2] = a;
            sq += a * a;
        }
        // split f32 -> bf16 hi/lo (truncation) and pack
        unsigned hw[8], lw[8];
        #pragma unroll
        for (int j = 0; j < 8; ++j) {
            float f0 = tf[2 * j], f1 = tf[2 * j + 1];
            unsigned u0 = __float_as_uint(f0) & 0xFFFF0000u;
            unsigned u1 = __float_as_uint(f1) & 0xFFFF0000u;
            hw[j] = (u0 >> 16) | u1;
            float r0 = f0 - __uint_as_float(u0);
            float r1 = f1 - __uint_as_float(u1);
            lw[j] = (__float_as_uint(r0) >> 16) | (__float_as_uint(r1) & 0xFFFF0000u);
        }
        short* tr = &Tsh[tid * TST];
        *(uint4*)(tr + 0)  = make_uint4(hw[0], hw[1], hw[2], hw[3]);
        *(uint4*)(tr + 8)  = make_uint4(hw[4], hw[5], hw[6], hw[7]);
        *(uint4*)(tr + 16) = make_uint4(lw[0], lw[1], lw[2], lw[3]);
        *(uint4*)(tr + 24) = make_uint4(lw[4], lw[5], lw[6], lw[7]);
        *(float*)(tr + 32) = 0.5f * sq;
    }

    if (tid < NSV) {
        // SV MLP -> Shi/Slo + hsq + proj
        const float* xp = x_sv + (size_t)(b * NSV + tid) * 2;
        float x0 = xp[0], x1 = xp[1];
        float hb[HH];
        #pragma unroll
        for (int h = 0; h < HH; ++h)
            hb[h] = elu_f(x0 * W1s[h] + x1 * W1s[HH + h] + b1s[h]);
        float o[HH], sq = 0.0f;
        #pragma unroll
        for (int h2 = 0; h2 < HH; ++h2) {
            float a = b2s[h2];
            #pragma unroll
            for (int h = 0; h < HH; ++h) a += hb[h] * W2s[h * HH + h2];
            o[h2] = a;
            sq += a * a;
        }
        unsigned hw[8], lw[8];
        #pragma unroll
        for (int j = 0; j < 8; ++j) {
            float f0 = o[2 * j], f1 = o[2 * j + 1];
            unsigned u0 = __float_as_uint(f0) & 0xFFFF0000u;
            unsigned u1 = __float_as_uint(f1) & 0xFFFF0000u;
            hw[j] = (u0 >> 16) | u1;
            float r0 = f0 - __uint_as_float(u0);
            float r1 = f1 - __uint_as_float(u1);
            lw[j] = (__float_as_uint(r0) >> 16) | (__float_as_uint(r1) & 0xFFFF0000u);
        }
        short* sh = &ShiS[tid * SST];
        short* sl = &SloS[tid * SST];
        *(uint4*)(sh + 0) = make_uint4(hw[0], hw[1], hw[2], hw[3]);
        *(uint4*)(sh + 8) = make_uint4(hw[4], hw[5], hw[6], hw[7]);
        *(uint4*)(sl + 0) = make_uint4(lw[0], lw[1], lw[2], lw[3]);
        *(uint4*)(sl + 8) = make_uint4(lw[4], lw[5], lw[6], lw[7]);
        hsqS[tid] = 0.5f * sq;
        #pragma unroll
        for (int h = 0; h < HH; ++h) {
            float a = 0.0f;
            #pragma unroll
            for (int j = 0; j < HH; ++j) a += o[j] * We[(HH + j) * HH + h];
            proj[tid][h] = a;
        }
    } else if (tid < NSV + HH) {
        int j = tid - NSV;
        float a = 0.0f;
        #pragma unroll
        for (int h = 0; h < HH; ++h)
            a += (We[j * HH + h] - We[(HH + j) * HH + h]) * Wo[h];
        ucS[j] = a;
    } else if (tid == NSV + HH) {
        float a = bo[0];
        #pragma unroll
        for (int h = 0; h < HH; ++h) a += be[h] * Wo[h];
        ucS[HH] = a;
    }

    __syncthreads();

    // ================= phase B: MFMA distances + top-8 =================
    {
        const int lane = tid & 63;
        const int w    = tid >> 6;        // wave 0..7
        const int c    = lane & 15;       // track col within tile
        const int g    = lane >> 4;       // 0..3
        const int g4   = g << 2;          // sv row base within tile
        const int gk   = g << 3;          // B k-chunk (shorts)
        const int gah  = (g & 1) << 3;    // A k-chunk (shorts, dup)

        #pragma unroll
        for (int i = 0; i < 4; ++i) {
            const int tt  = w + 8 * i;            // track tile 0..31
            const int trk = tt * 16 + c;
            const short* tb = &Tsh[trk * TST];
            bf16x8 bfrag = *(const bf16x8*)(tb + gk);
            float  htsq  = *(const float*)(tb + 32);

            f32x4 acc[8];
            #pragma unroll
            for (int ss = 0; ss < 8; ++ss) acc[ss] = (f32x4){0.f, 0.f, 0.f, 0.f};
            #pragma unroll
            for (int ss = 0; ss < 8; ++ss) {
                const int svr = ss * 16 + c;
                bf16x8 a1 = *(const bf16x8*)&ShiS[svr * SST + gah];
                bf16x8 a2 = *(const bf16x8*)&SloS[svr * SST + gah];
                acc[ss] = __builtin_amdgcn_mfma_f32_16x16x32_bf16(a1, bfrag, acc[ss], 0, 0, 0);
                acc[ss] = __builtin_amdgcn_mfma_f32_16x16x32_bf16(a2, bfrag, acc[ss], 0, 0, 0);
            }

            unsigned k0 = ~0u, k1 = ~0u, k2 = ~0u, k3 = ~0u,
                     k4 = ~0u, k5 = ~0u, k6 = ~0u, k7 = ~0u;
            #define CHAIN(v)                                               \
                do {                                                       \
                    unsigned nk0 = umin_u(v, k0);                          \
                    unsigned nk1 = med3u(v, k0, k1);                       \
                    unsigned nk2 = med3u(v, k1, k2);                       \
                    unsigned nk3 = med3u(v, k2, k3);                       \
                    unsigned nk4 = med3u(v, k3, k4);                       \
                    unsigned nk5 = med3u(v, k4, k5);                       \
                    unsigned nk6 = med3u(v, k5, k6);                       \
                    unsigned nk7 = med3u(v, k6, k7);                       \
                    k0 = nk0; k1 = nk1; k2 = nk2; k3 = nk3;                \
                    k4 = nk4; k5 = nk5; k6 = nk6; k7 = nk7;                \
                } while (0)
            #pragma unroll
            for (int ss = 0; ss < 8; ++ss) {
                f32x4 hq = *(const f32x4*)&hsqS[ss * 16 + g4];
                float e0 = fmaxf((htsq + hq.x) - acc[ss].x, 0.0f);
                float e1 = fmaxf((htsq + hq.y) - acc[ss].y, 0.0f);
                float e2 = fmaxf((htsq + hq.z) - acc[ss].z, 0.0f);
                float e3 = fmaxf((htsq + hq.w) - acc[ss].w, 0.0f);
                unsigned v0 = (__float_as_uint(e0) & 0xFFFFFF80u) | (unsigned)(g4 + ss * 16 + 0);
                CHAIN(v0);
                unsigned v1 = (__float_as_uint(e1) & 0xFFFFFF80u) | (unsigned)(g4 + ss * 16 + 1);
                CHAIN(v1);
                unsigned v2 = (__float_as_uint(e2) & 0xFFFFFF80u) | (unsigned)(g4 + ss * 16 + 2);
                CHAIN(v2);
                unsigned v3 = (__float_as_uint(e3) & 0xFFFFFF80u) | (unsigned)(g4 + ss * 16 + 3);
                CHAIN(v3);
            }
            #undef CHAIN

            // merge the 4 lanes (g=0..3) holding this track: sets are disjoint
            // stage 1: partner lane^32 (sorted+sorted -> bitonic set of 8 smallest)
            unsigned m0 = umin_u(k0, __shfl_xor(k7, 32, 64));
            unsigned m1 = umin_u(k1, __shfl_xor(k6, 32, 64));
            unsigned m2 = umin_u(k2, __shfl_xor(k5, 32, 64));
            unsigned m3 = umin_u(k3, __shfl_xor(k4, 32, 64));
            unsigned m4 = umin_u(k4, __shfl_xor(k3, 32, 64));
            unsigned m5 = umin_u(k5, __shfl_xor(k2, 32, 64));
            unsigned m6 = umin_u(k6, __shfl_xor(k1, 32, 64));
            unsigned m7 = umin_u(k7, __shfl_xor(k0, 32, 64));
            // bitonic-8 resort (ascending)
            #define CEX(a, bq) do { unsigned _lo = umin_u(a, bq); unsigned _hi = umax_u(a, bq); a = _lo; bq = _hi; } while (0)
            CEX(m0, m4); CEX(m1, m5); CEX(m2, m6); CEX(m3, m7);
            CEX(m0, m2); CEX(m1, m3); CEX(m4, m6); CEX(m5, m7);
            CEX(m0, m1); CEX(m2, m3); CEX(m4, m5); CEX(m6, m7);
            #undef CEX
            // stage 2: partner lane^16 -> final top-8 set (unsorted ok)
            unsigned f0 = umin_u(m0, __shfl_xor(m7, 16, 64));
            unsigned f1 = umin_u(m1, __shfl_xor(m6, 16, 64));
            unsigned f2 = umin_u(m2, __shfl_xor(m5, 16, 64));
            unsigned f3 = umin_u(m3, __shfl_xor(m4, 16, 64));
            unsigned f4 = umin_u(m4, __shfl_xor(m3, 16, 64));
            unsigned f5 = umin_u(m5, __shfl_xor(m2, 16, 64));
            unsigned f6 = umin_u(m6, __shfl_xor(m1, 16, 64));
            unsigned f7 = umin_u(m7, __shfl_xor(m0, 16, 64));
            if (g == 0) {
                *(uint4*)&knnS[trk * KK]     = make_uint4(f0, f1, f2, f3);
                *(uint4*)&knnS[trk * KK + 4] = make_uint4(f4, f5, f6, f7);
            }
        }
    }

    __syncthreads();

    // ================= phase C: per-thread epilogue =================
    float local;
    {
        // reconstruct tf (hi+lo, err ~2^-16 — negligible through u·tf)
        const short* tr = &Tsh[tid * TST];
        uint4 ha = *(const uint4*)(tr + 0);
        uint4 hbq = *(const uint4*)(tr + 8);
        uint4 la = *(const uint4*)(tr + 16);
        uint4 lb = *(const uint4*)(tr + 24);
        unsigned hwv[8] = {ha.x, ha.y, ha.z, ha.w, hbq.x, hbq.y, hbq.z, hbq.w};
        unsigned lwv[8] = {la.x, la.y, la.z, la.w, lb.x, lb.y, lb.z, lb.w};
        float tf[HH];
        #pragma unroll
        for (int j = 0; j < 8; ++j) {
            tf[2 * j]     = __uint_as_float(hwv[j] << 16) + __uint_as_float(lwv[j] << 16);
            tf[2 * j + 1] = __uint_as_float(hwv[j] & 0xFFFF0000u) + __uint_as_float(lwv[j] & 0xFFFF0000u);
        }
        float acc = ucS[HH];
        #pragma unroll
        for (int h = 0; h < HH; ++h) acc = fmaf(tf[h], ucS[h], acc);

        uint4 ka = *(const uint4*)&knnS[tid * KK];
        uint4 kb = *(const uint4*)&knnS[tid * KK + 4];
        unsigned idx[KK] = {ka.x, ka.y, ka.z, ka.w, kb.x, kb.y, kb.z, kb.w};
        float mx[HH];
        #pragma unroll
        for (int h = 0; h < HH; ++h) mx[h] = -INFINITY;
        #pragma unroll
        for (int q = 0; q < KK; ++q) {
            const float* pr = &proj[idx[q] & 127u][0];
            #pragma unroll
            for (int h4 = 0; h4 < 4; ++h4) {
                float4 p = *(const float4*)&pr[h4 * 4];
                mx[h4 * 4 + 0] = fmaxf(mx[h4 * 4 + 0], p.x);
                mx[h4 * 4 + 1] = fmaxf(mx[h4 * 4 + 1], p.y);
                mx[h4 * 4 + 2] = fmaxf(mx[h4 * 4 + 2], p.z);
                mx[h4 * 4 + 3] = fmaxf(mx[h4 * 4 + 3], p.w);
            }
        }
        #pragma unroll
        for (int h = 0; h < HH; ++h) acc = fmaf(mx[h], Wo[h], acc);

        float t = __builtin_amdgcn_exp2f(acc * -1.44269504088896341f);
        local = __builtin_amdgcn_rcpf(1.0f + t);
    }

    // ---- block mean-pool over 512 tracks ----
    #pragma unroll
    for (int off = 32; off > 0; off >>= 1)
        local += __shfl_down(local, off, 64);
    if ((tid & 63) == 0) sred[tid >> 6] = local;
    __syncthreads();
    if (tid == 0) {
        float tot = 0.0f;
        #pragma unroll
        for (int w = 0; w < TPB / 64; ++w) tot += sred[w];
        out[b]      = tot * (1.0f / NTRK);
        out[BB + b] = (float)b;
    }
}

extern "C" void kernel_launch(void* const* d_in, const int* in_sizes, int n_in,
                              void* d_out, int out_size, void* d_ws, size_t ws_size,
                              hipStream_t stream) {
    const float* x_sv  = (const float*)d_in[0];
    const float* x_trk = (const float*)d_in[1];
    const float* W1s = (const float*)d_in[4];
    const float* b1s = (const float*)d_in[5];
    const float* W2s = (const float*)d_in[6];
    const float* b2s = (const float*)d_in[7];
    const float* W1t = (const float*)d_in[8];
    const float* b1t = (const float*)d_in[9];
    const float* W2t = (const float*)d_in[10];
    const float* b2t = (const float*)d_in[11];
    const float* We  = (const float*)d_in[12];
    const float* be  = (const float*)d_in[13];
    const float* Wo  = (const float*)d_in[14];
    const float* bo  = (const float*)d_in[15];
    float* out = (float*)d_out;

    fused_all<<<BB, TPB, 0, stream>>>(x_sv, x_trk,
                                      W1s, b1s, W2s, b2s,
                                      W1t, b1t, W2t, b2t,
                                      We, be, Wo, bo,
                                      out);
}